// Round 1
// baseline (1288.007 us; speedup 1.0000x reference)
//
#include <hip/hip_runtime.h>
#include <hip/hip_bf16.h>

using u16 = unsigned short;
using u32 = unsigned int;

typedef __bf16 bf16x8 __attribute__((ext_vector_type(8)));
typedef float f32x4 __attribute__((ext_vector_type(4)));
typedef float f32x4v __attribute__((ext_vector_type(4)));
typedef unsigned short u16x8 __attribute__((ext_vector_type(8)));

constexpr int NT  = 8192;   // B*T tokens
constexpr int DIM = 1024;
constexpr int FF  = 4096;
constexpr int NE  = 8;      // experts

constexpr int BM = 128, BN = 128, BK = 64;

__device__ inline u16 f2bf(float f) {
    u32 u = __float_as_uint(f);
    u32 r = (u + 0x7fffu + ((u >> 16) & 1u)) >> 16;
    return (u16)r;
}

// ---------------- router: logits -> top2 -> softmax weights ----------------
__global__ __launch_bounds__(256) void k_router(const float* __restrict__ x,
                                                const float* __restrict__ Wr,
                                                int* __restrict__ topi,
                                                float* __restrict__ topw,
                                                int* __restrict__ counts) {
    int w = threadIdx.x >> 6, lane = threadIdx.x & 63;
    int t = blockIdx.x * 4 + w;
    const float* xt = x + (size_t)t * DIM;
    float acc[NE];
#pragma unroll
    for (int e = 0; e < NE; e++) acc[e] = 0.f;
    for (int i = 0; i < DIM / 64; i++) {
        int d = i * 64 + lane;
        float xv = xt[d];
#pragma unroll
        for (int e = 0; e < NE; e++) acc[e] += xv * Wr[e * DIM + d];
    }
#pragma unroll
    for (int e = 0; e < NE; e++) {
#pragma unroll
        for (int off = 32; off >= 1; off >>= 1) acc[e] += __shfl_xor(acc[e], off, 64);
    }
    if (lane == 0) {
        int b0 = 0; float v0 = acc[0];
        for (int e = 1; e < NE; e++) if (acc[e] > v0) { v0 = acc[e]; b0 = e; }
        int b1 = -1; float v1 = -INFINITY;
        for (int e = 0; e < NE; e++) if (e != b0 && acc[e] > v1) { v1 = acc[e]; b1 = e; }
        float e1 = __expf(v1 - v0);
        float w0 = 1.f / (1.f + e1);
        topi[t * 2] = b0; topi[t * 2 + 1] = b1;
        topw[t * 2] = w0; topw[t * 2 + 1] = 1.f - w0;
        atomicAdd(&counts[b0], 1);
        atomicAdd(&counts[b1], 1);
    }
}

__global__ void k_prefix(const int* __restrict__ counts, int* __restrict__ offs,
                         int* __restrict__ cursor) {
    if (threadIdx.x == 0) {
        int s = 0;
        for (int e = 0; e < NE; e++) { offs[e] = s; cursor[e] = s; s += counts[e]; }
    }
}

__global__ __launch_bounds__(256) void k_build(const int* __restrict__ topi,
                                               const float* __restrict__ topw,
                                               int* __restrict__ cursor,
                                               int* __restrict__ rows,
                                               float* __restrict__ roww) {
    int t = blockIdx.x * 256 + threadIdx.x;
    if (t >= NT) return;
#pragma unroll
    for (int s = 0; s < 2; s++) {
        int e = topi[t * 2 + s];
        int p = atomicAdd(&cursor[e], 1);
        rows[p] = t * 2 + s;
        roww[p] = topw[t * 2 + s];
    }
}

// ---------------- fp32 -> bf16 convert (x) ----------------
__global__ __launch_bounds__(256) void k_cvt(const float* __restrict__ in,
                                             u16* __restrict__ out, int n) {
    int i = blockIdx.x * 256 + threadIdx.x;
    int base = i * 8;
    if (base >= n) return;
    const f32x4v* in4 = reinterpret_cast<const f32x4v*>(in + base);
    f32x4v a = in4[0], b = in4[1];
    u16x8 o;
#pragma unroll
    for (int j = 0; j < 4; j++) { o[j] = f2bf(a[j]); o[j + 4] = f2bf(b[j]); }
    *reinterpret_cast<u16x8*>(out + base) = o;
}

// ---------------- transpose + convert: in [R][C] fp32 -> out [C][R] bf16 ----------------
__global__ __launch_bounds__(256) void k_tcvt(const float* __restrict__ in,
                                              u16* __restrict__ out, int R, int C) {
    __shared__ float tile[32][33];
    int e = blockIdx.z;
    const float* pin = in + (size_t)e * R * C;
    u16* pout = out + (size_t)e * R * C;
    int c0 = blockIdx.x * 32, r0 = blockIdx.y * 32;
    int lc = threadIdx.x & 31, lr = threadIdx.x >> 5;   // 8 row-groups
#pragma unroll
    for (int i = 0; i < 4; i++) {
        int r = lr + i * 8;
        tile[r][lc] = pin[(size_t)(r0 + r) * C + c0 + lc];
    }
    __syncthreads();
#pragma unroll
    for (int i = 0; i < 4; i++) {
        int cc = lr + i * 8;   // tile column = output row
        pout[(size_t)(c0 + cc) * R + r0 + lc] = f2bf(tile[lc][cc]);
    }
}

// ---------------- GEMM1: H[row, ff] = gelu( x[token] @ W1[e] ), bf16 MFMA ----------------
__global__ __launch_bounds__(256) void k_gemm1(const u16* __restrict__ xbf,
                                               const u16* __restrict__ w1t, // [E][FF][DIM]
                                               const int* __restrict__ rows,
                                               const int* __restrict__ offs,
                                               const int* __restrict__ counts,
                                               u16* __restrict__ H) {
    int e = blockIdx.z;
    int cnt = counts[e];
    int m0 = blockIdx.x * BM;
    if (m0 >= cnt) return;
    int n0 = blockIdx.y * BN;
    int off = offs[e];

    __shared__ __align__(16) u16 Als[BM * BK];
    __shared__ __align__(16) u16 Bls[BN * BK];

    int tid = threadIdx.x;
    int lane = tid & 63, wid = tid >> 6;
    int wr = wid >> 1, wc = wid & 1;

    f32x4 acc[4][4];
#pragma unroll
    for (int i = 0; i < 4; i++)
#pragma unroll
        for (int j = 0; j < 4; j++) acc[i][j] = (f32x4)(0.f);

    const u16* aptr[4]; int asl[4];
    const u16* bptr[4]; int bsl[4];
#pragma unroll
    for (int i = 0; i < 4; i++) {
        int c = i * 256 + tid;
        int row = c >> 3, s = c & 7;
        int lrow = m0 + row;
        int tok = (lrow < cnt) ? (rows[off + lrow] >> 1) : 0;
        aptr[i] = xbf + (size_t)tok * DIM + s * 8;
        asl[i]  = row * BK + ((s ^ (row & 7)) * 8);
        bptr[i] = w1t + (size_t)e * FF * DIM + (size_t)(n0 + row) * DIM + s * 8;
        bsl[i]  = row * BK + ((s ^ (row & 7)) * 8);
    }

    for (int kt = 0; kt < DIM / BK; ++kt) {
        u16x8 av[4], bv[4];
#pragma unroll
        for (int i = 0; i < 4; i++) av[i] = *reinterpret_cast<const u16x8*>(aptr[i] + kt * BK);
#pragma unroll
        for (int i = 0; i < 4; i++) bv[i] = *reinterpret_cast<const u16x8*>(bptr[i] + kt * BK);
        __syncthreads();
#pragma unroll
        for (int i = 0; i < 4; i++) *reinterpret_cast<u16x8*>(&Als[asl[i]]) = av[i];
#pragma unroll
        for (int i = 0; i < 4; i++) *reinterpret_cast<u16x8*>(&Bls[bsl[i]]) = bv[i];
        __syncthreads();
#pragma unroll
        for (int kk = 0; kk < 2; kk++) {
            bf16x8 af[4], bfr[4];
#pragma unroll
            for (int mi = 0; mi < 4; mi++) {
                int row = wr * 64 + mi * 16 + (lane & 15);
                int s = (kk * 4 + (lane >> 4)) ^ (row & 7);
                af[mi] = *reinterpret_cast<const bf16x8*>(&Als[row * BK + s * 8]);
            }
#pragma unroll
            for (int nj = 0; nj < 4; nj++) {
                int row = wc * 64 + nj * 16 + (lane & 15);
                int s = (kk * 4 + (lane >> 4)) ^ (row & 7);
                bfr[nj] = *reinterpret_cast<const bf16x8*>(&Bls[row * BK + s * 8]);
            }
#pragma unroll
            for (int mi = 0; mi < 4; mi++)
#pragma unroll
                for (int nj = 0; nj < 4; nj++)
                    acc[mi][nj] = __builtin_amdgcn_mfma_f32_16x16x32_bf16(af[mi], bfr[nj], acc[mi][nj], 0, 0, 0);
        }
    }

    // epilogue: exact GELU -> bf16 H
#pragma unroll
    for (int mi = 0; mi < 4; mi++) {
#pragma unroll
        for (int r = 0; r < 4; r++) {
            int lrow = m0 + wr * 64 + mi * 16 + ((lane >> 4) << 2) + r;
            if (lrow >= cnt) continue;
            u16* hp = H + (size_t)(off + lrow) * FF + n0 + wc * 64;
#pragma unroll
            for (int nj = 0; nj < 4; nj++) {
                float v = acc[mi][nj][r];
                v = 0.5f * v * (1.f + erff(v * 0.70710678118f));
                hp[nj * 16 + (lane & 15)] = f2bf(v);
            }
        }
    }
}

// ---------------- GEMM2: out[token] += w * (H[row] @ W2[e]) ----------------
__global__ __launch_bounds__(256) void k_gemm2(const u16* __restrict__ H,
                                               const u16* __restrict__ w2t, // [E][DIM][FF]
                                               const int* __restrict__ rows,
                                               const float* __restrict__ roww,
                                               const int* __restrict__ offs,
                                               const int* __restrict__ counts,
                                               float* __restrict__ out) {
    int e = blockIdx.z;
    int cnt = counts[e];
    int m0 = blockIdx.x * BM;
    if (m0 >= cnt) return;
    int n0 = blockIdx.y * BN;
    int off = offs[e];

    __shared__ __align__(16) u16 Als[BM * BK];
    __shared__ __align__(16) u16 Bls[BN * BK];

    int tid = threadIdx.x;
    int lane = tid & 63, wid = tid >> 6;
    int wr = wid >> 1, wc = wid & 1;

    f32x4 acc[4][4];
#pragma unroll
    for (int i = 0; i < 4; i++)
#pragma unroll
        for (int j = 0; j < 4; j++) acc[i][j] = (f32x4)(0.f);

    const u16* aptr[4]; int asl[4];
    const u16* bptr[4]; int bsl[4];
#pragma unroll
    for (int i = 0; i < 4; i++) {
        int c = i * 256 + tid;
        int row = c >> 3, s = c & 7;
        int lrow = m0 + row;
        int grow = off + ((lrow < cnt) ? lrow : (cnt - 1));
        aptr[i] = H + (size_t)grow * FF + s * 8;
        asl[i]  = row * BK + ((s ^ (row & 7)) * 8);
        bptr[i] = w2t + (size_t)e * DIM * FF + (size_t)(n0 + row) * FF + s * 8;
        bsl[i]  = row * BK + ((s ^ (row & 7)) * 8);
    }

    for (int kt = 0; kt < FF / BK; ++kt) {
        u16x8 av[4], bv[4];
#pragma unroll
        for (int i = 0; i < 4; i++) av[i] = *reinterpret_cast<const u16x8*>(aptr[i] + kt * BK);
#pragma unroll
        for (int i = 0; i < 4; i++) bv[i] = *reinterpret_cast<const u16x8*>(bptr[i] + kt * BK);
        __syncthreads();
#pragma unroll
        for (int i = 0; i < 4; i++) *reinterpret_cast<u16x8*>(&Als[asl[i]]) = av[i];
#pragma unroll
        for (int i = 0; i < 4; i++) *reinterpret_cast<u16x8*>(&Bls[bsl[i]]) = bv[i];
        __syncthreads();
#pragma unroll
        for (int kk = 0; kk < 2; kk++) {
            bf16x8 af[4], bfr[4];
#pragma unroll
            for (int mi = 0; mi < 4; mi++) {
                int row = wr * 64 + mi * 16 + (lane & 15);
                int s = (kk * 4 + (lane >> 4)) ^ (row & 7);
                af[mi] = *reinterpret_cast<const bf16x8*>(&Als[row * BK + s * 8]);
            }
#pragma unroll
            for (int nj = 0; nj < 4; nj++) {
                int row = wc * 64 + nj * 16 + (lane & 15);
                int s = (kk * 4 + (lane >> 4)) ^ (row & 7);
                bfr[nj] = *reinterpret_cast<const bf16x8*>(&Bls[row * BK + s * 8]);
            }
#pragma unroll
            for (int mi = 0; mi < 4; mi++)
#pragma unroll
                for (int nj = 0; nj < 4; nj++)
                    acc[mi][nj] = __builtin_amdgcn_mfma_f32_16x16x32_bf16(af[mi], bfr[nj], acc[mi][nj], 0, 0, 0);
        }
    }

#pragma unroll
    for (int mi = 0; mi < 4; mi++) {
#pragma unroll
        for (int r = 0; r < 4; r++) {
            int lrow = m0 + wr * 64 + mi * 16 + ((lane >> 4) << 2) + r;
            if (lrow >= cnt) continue;
            int rv = rows[off + lrow];
            float wgt = roww[off + lrow];
            float* op = out + (size_t)(rv >> 1) * DIM + n0 + wc * 64;
#pragma unroll
            for (int nj = 0; nj < 4; nj++)
                atomicAdd(&op[nj * 16 + (lane & 15)], wgt * acc[mi][nj][r]);
        }
    }
}

extern "C" void kernel_launch(void* const* d_in, const int* in_sizes, int n_in,
                              void* d_out, int out_size, void* d_ws, size_t ws_size,
                              hipStream_t stream) {
    const float* x  = (const float*)d_in[0];
    const float* Wr = (const float*)d_in[1];
    const float* W1 = (const float*)d_in[2];
    const float* W2 = (const float*)d_in[3];
    float* out = (float*)d_out;

    char* w = (char*)d_ws;
    size_t o = 0;
    auto carve = [&](size_t bytes) -> void* {
        void* p = w + o;
        o = (o + bytes + 255) & ~(size_t)255;
        return p;
    };
    int*   counts = (int*)carve(NE * 4);
    int*   offs   = (int*)carve(NE * 4);
    int*   cursor = (int*)carve(NE * 4);
    int*   topi   = (int*)carve((size_t)NT * 2 * 4);
    float* topw   = (float*)carve((size_t)NT * 2 * 4);
    int*   rows   = (int*)carve((size_t)NT * 2 * 4);
    float* roww   = (float*)carve((size_t)NT * 2 * 4);
    u16*   xbf    = (u16*)carve((size_t)NT * DIM * 2);
    u16*   w1t    = (u16*)carve((size_t)NE * DIM * FF * 2);
    u16*   w2t    = (u16*)carve((size_t)NE * DIM * FF * 2);
    u16*   Hbuf   = (u16*)carve((size_t)NT * 2 * FF * 2);
    (void)ws_size; (void)in_sizes; (void)n_in; (void)out_size;

    hipMemsetAsync(counts, 0, NE * 4, stream);
    hipMemsetAsync(d_out, 0, (size_t)NT * DIM * 4, stream);

    k_router<<<NT / 4, 256, 0, stream>>>(x, Wr, topi, topw, counts);
    k_prefix<<<1, 64, 0, stream>>>(counts, offs, cursor);
    k_build<<<NT / 256, 256, 0, stream>>>(topi, topw, cursor, rows, roww);
    k_cvt<<<(NT * DIM / 8) / 256, 256, 0, stream>>>(x, xbf, NT * DIM);
    {
        dim3 g(FF / 32, DIM / 32, NE);
        k_tcvt<<<g, 256, 0, stream>>>(W1, w1t, DIM, FF);
    }
    {
        dim3 g(DIM / 32, FF / 32, NE);
        k_tcvt<<<g, 256, 0, stream>>>(W2, w2t, FF, DIM);
    }
    {
        dim3 g(NT / BM, FF / BN, NE);
        k_gemm1<<<g, 256, 0, stream>>>(xbf, w1t, rows, offs, counts, Hbuf);
    }
    {
        dim3 g(NT / BM, DIM / BN, NE);
        k_gemm2<<<g, 256, 0, stream>>>(Hbuf, w2t, rows, roww, offs, counts, out);
    }
}

// Round 2
// 1274.787 us; speedup vs baseline: 1.0104x; 1.0104x over previous
//
#include <hip/hip_runtime.h>
#include <hip/hip_bf16.h>

using u16 = unsigned short;
using u32 = unsigned int;

typedef __bf16 bf16x8 __attribute__((ext_vector_type(8)));
typedef float f32x4 __attribute__((ext_vector_type(4)));
typedef float f32x4v __attribute__((ext_vector_type(4)));
typedef unsigned short u16x8 __attribute__((ext_vector_type(8)));

constexpr int NT  = 8192;   // B*T tokens
constexpr int DIM = 1024;
constexpr int FF  = 4096;
constexpr int NE  = 8;      // experts

constexpr int BM = 128, BN = 128, BK = 64;

__device__ inline u16 f2bf(float f) {
    u32 u = __float_as_uint(f);
    u32 r = (u + 0x7fffu + ((u >> 16) & 1u)) >> 16;
    return (u16)r;
}

// direct global->LDS, 16B per lane, wave-uniform LDS base + lane*16
__device__ inline void gload16(const void* g, void* l) {
    __builtin_amdgcn_global_load_lds(
        (const __attribute__((address_space(1))) void*)g,
        (__attribute__((address_space(3))) void*)l, 16, 0, 0);
}

// ---------------- router: logits -> top2 -> softmax weights ----------------
__global__ __launch_bounds__(256) void k_router(const float* __restrict__ x,
                                                const float* __restrict__ Wr,
                                                int* __restrict__ topi,
                                                float* __restrict__ topw,
                                                int* __restrict__ counts) {
    int w = threadIdx.x >> 6, lane = threadIdx.x & 63;
    int t = blockIdx.x * 4 + w;
    const float* xt = x + (size_t)t * DIM;
    float acc[NE];
#pragma unroll
    for (int e = 0; e < NE; e++) acc[e] = 0.f;
    for (int i = 0; i < DIM / 64; i++) {
        int d = i * 64 + lane;
        float xv = xt[d];
#pragma unroll
        for (int e = 0; e < NE; e++) acc[e] += xv * Wr[e * DIM + d];
    }
#pragma unroll
    for (int e = 0; e < NE; e++) {
#pragma unroll
        for (int off = 32; off >= 1; off >>= 1) acc[e] += __shfl_xor(acc[e], off, 64);
    }
    if (lane == 0) {
        int b0 = 0; float v0 = acc[0];
        for (int e = 1; e < NE; e++) if (acc[e] > v0) { v0 = acc[e]; b0 = e; }
        int b1 = -1; float v1 = -INFINITY;
        for (int e = 0; e < NE; e++) if (e != b0 && acc[e] > v1) { v1 = acc[e]; b1 = e; }
        float e1 = __expf(v1 - v0);
        float w0 = 1.f / (1.f + e1);
        topi[t * 2] = b0; topi[t * 2 + 1] = b1;
        topw[t * 2] = w0; topw[t * 2 + 1] = 1.f - w0;
        atomicAdd(&counts[b0], 1);
        atomicAdd(&counts[b1], 1);
    }
}

__global__ void k_prefix(const int* __restrict__ counts, int* __restrict__ offs,
                         int* __restrict__ cursor) {
    if (threadIdx.x == 0) {
        int s = 0;
        for (int e = 0; e < NE; e++) { offs[e] = s; cursor[e] = s; s += counts[e]; }
    }
}

__global__ __launch_bounds__(256) void k_build(const int* __restrict__ topi,
                                               const float* __restrict__ topw,
                                               int* __restrict__ cursor,
                                               int* __restrict__ rows,
                                               float* __restrict__ roww) {
    int t = blockIdx.x * 256 + threadIdx.x;
    if (t >= NT) return;
#pragma unroll
    for (int s = 0; s < 2; s++) {
        int e = topi[t * 2 + s];
        int p = atomicAdd(&cursor[e], 1);
        rows[p] = t * 2 + s;
        roww[p] = topw[t * 2 + s];
    }
}

// ---------------- fp32 -> bf16 convert (x) ----------------
__global__ __launch_bounds__(256) void k_cvt(const float* __restrict__ in,
                                             u16* __restrict__ out, int n) {
    int i = blockIdx.x * 256 + threadIdx.x;
    int base = i * 8;
    if (base >= n) return;
    const f32x4v* in4 = reinterpret_cast<const f32x4v*>(in + base);
    f32x4v a = in4[0], b = in4[1];
    u16x8 o;
#pragma unroll
    for (int j = 0; j < 4; j++) { o[j] = f2bf(a[j]); o[j + 4] = f2bf(b[j]); }
    *reinterpret_cast<u16x8*>(out + base) = o;
}

// ---------------- transpose + convert: in [R][C] fp32 -> out [C][R] bf16 ----------------
// 64x64 tile, float4 loads, u16x8 stores.
__global__ __launch_bounds__(256) void k_tcvt(const float* __restrict__ in,
                                              u16* __restrict__ out, int R, int C) {
    __shared__ float tile[64][65];
    int e = blockIdx.z;
    const float* pin = in + (size_t)e * R * C;
    u16* pout = out + (size_t)e * R * C;
    int c0 = blockIdx.x * 64, r0 = blockIdx.y * 64;
    int t = threadIdx.x;
    int lc = (t & 15) * 4, lr = t >> 4;     // 16 rows per pass
#pragma unroll
    for (int i = 0; i < 4; i++) {
        int r = lr + i * 16;
        f32x4v v = *reinterpret_cast<const f32x4v*>(&pin[(size_t)(r0 + r) * C + c0 + lc]);
        tile[r][lc] = v[0]; tile[r][lc + 1] = v[1];
        tile[r][lc + 2] = v[2]; tile[r][lc + 3] = v[3];
    }
    __syncthreads();
    int oc = (t & 7) * 8;                   // 8 threads per out-row
    int orow = t >> 3;                      // 32 out-rows per pass
#pragma unroll
    for (int i = 0; i < 2; i++) {
        int cc = orow + i * 32;             // tile column = out row
        u16x8 o;
#pragma unroll
        for (int j = 0; j < 8; j++) o[j] = f2bf(tile[oc + j][cc]);
        *reinterpret_cast<u16x8*>(&pout[(size_t)(c0 + cc) * R + r0 + oc]) = o;
    }
}

// ---------------- GEMM1: H[row, ff] = gelu( x[token] @ W1[e] ), m97-style gload_lds ----------------
__global__ __launch_bounds__(256) void k_gemm1(const u16* __restrict__ xbf,
                                               const u16* __restrict__ w1t, // [E][FF][DIM]
                                               const int* __restrict__ rows,
                                               const int* __restrict__ offs,
                                               const int* __restrict__ counts,
                                               u16* __restrict__ H) {
    int e = blockIdx.z;
    int cnt = counts[e];
    int m0 = blockIdx.x * BM;
    if (m0 >= cnt) return;
    int n0 = blockIdx.y * BN;
    int off = offs[e];

    __shared__ __align__(16) u16 Als[BM * BK];
    __shared__ __align__(16) u16 Bls[BN * BK];

    int tid = threadIdx.x;
    int lane = tid & 63, wid = tid >> 6;
    int wr = wid >> 1, wc = wid & 1;

    f32x4 acc[4][4];
#pragma unroll
    for (int i = 0; i < 4; i++)
#pragma unroll
        for (int j = 0; j < 4; j++) acc[i][j] = (f32x4)(0.f);

    // per-thread staging sources: chunk c = i*256 + tid; row = c>>3 = i*32 + (tid>>3);
    // logical col-chunk g = (c&7) ^ (row&7)  (pre-swizzled source so linear LDS write
    // lands at the swizzled position the reader expects)
    const u16* aSrc[4];
    const u16* bSrc[4];
#pragma unroll
    for (int i = 0; i < 4; i++) {
        int row = i * 32 + (tid >> 3);
        int g = (tid & 7) ^ (row & 7);
        int lrow = m0 + row;
        int tok = (lrow < cnt) ? (rows[off + lrow] >> 1) : 0;
        aSrc[i] = xbf + (size_t)tok * DIM + g * 8;
        bSrc[i] = w1t + (size_t)e * FF * DIM + (size_t)(n0 + row) * DIM + g * 8;
    }
    int ldsBase = wid * 512;   // elems: wave-uniform chunk base (64 lanes * 8 elems)

    for (int kt = 0; kt < DIM / BK; ++kt) {
#pragma unroll
        for (int i = 0; i < 4; i++)
            gload16(aSrc[i] + kt * BK, &Als[i * 2048 + ldsBase]);
#pragma unroll
        for (int i = 0; i < 4; i++)
            gload16(bSrc[i] + kt * BK, &Bls[i * 2048 + ldsBase]);
        __syncthreads();   // drains vmcnt -> LDS tiles ready
#pragma unroll
        for (int kk = 0; kk < 2; kk++) {
            bf16x8 af[4], bfr[4];
#pragma unroll
            for (int mi = 0; mi < 4; mi++) {
                int row = wr * 64 + mi * 16 + (lane & 15);
                int s = (kk * 4 + (lane >> 4)) ^ (row & 7);
                af[mi] = *reinterpret_cast<const bf16x8*>(&Als[row * BK + s * 8]);
            }
#pragma unroll
            for (int nj = 0; nj < 4; nj++) {
                int row = wc * 64 + nj * 16 + (lane & 15);
                int s = (kk * 4 + (lane >> 4)) ^ (row & 7);
                bfr[nj] = *reinterpret_cast<const bf16x8*>(&Bls[row * BK + s * 8]);
            }
#pragma unroll
            for (int mi = 0; mi < 4; mi++)
#pragma unroll
                for (int nj = 0; nj < 4; nj++)
                    acc[mi][nj] = __builtin_amdgcn_mfma_f32_16x16x32_bf16(af[mi], bfr[nj], acc[mi][nj], 0, 0, 0);
        }
        __syncthreads();
    }

    // epilogue: exact GELU -> bf16 H
#pragma unroll
    for (int mi = 0; mi < 4; mi++) {
#pragma unroll
        for (int r = 0; r < 4; r++) {
            int lrow = m0 + wr * 64 + mi * 16 + ((lane >> 4) << 2) + r;
            if (lrow >= cnt) continue;
            u16* hp = H + (size_t)(off + lrow) * FF + n0 + wc * 64;
#pragma unroll
            for (int nj = 0; nj < 4; nj++) {
                float v = acc[mi][nj][r];
                v = 0.5f * v * (1.f + erff(v * 0.70710678118f));
                hp[nj * 16 + (lane & 15)] = f2bf(v);
            }
        }
    }
}

// ---------------- GEMM2: out[token] += w * (H[row] @ W2[e]) ----------------
__global__ __launch_bounds__(256) void k_gemm2(const u16* __restrict__ H,
                                               const u16* __restrict__ w2t, // [E][DIM][FF]
                                               const int* __restrict__ rows,
                                               const float* __restrict__ roww,
                                               const int* __restrict__ offs,
                                               const int* __restrict__ counts,
                                               float* __restrict__ out) {
    int e = blockIdx.z;
    int cnt = counts[e];
    int m0 = blockIdx.x * BM;
    if (m0 >= cnt) return;
    int n0 = blockIdx.y * BN;
    int off = offs[e];

    __shared__ __align__(16) u16 Als[BM * BK];
    __shared__ __align__(16) u16 Bls[BN * BK];

    int tid = threadIdx.x;
    int lane = tid & 63, wid = tid >> 6;
    int wr = wid >> 1, wc = wid & 1;

    f32x4 acc[4][4];
#pragma unroll
    for (int i = 0; i < 4; i++)
#pragma unroll
        for (int j = 0; j < 4; j++) acc[i][j] = (f32x4)(0.f);

    const u16* aSrc[4];
    const u16* bSrc[4];
#pragma unroll
    for (int i = 0; i < 4; i++) {
        int row = i * 32 + (tid >> 3);
        int g = (tid & 7) ^ (row & 7);
        int lrow = m0 + row;
        int grow = off + ((lrow < cnt) ? lrow : (cnt - 1));
        aSrc[i] = H + (size_t)grow * FF + g * 8;
        bSrc[i] = w2t + (size_t)e * DIM * FF + (size_t)(n0 + row) * FF + g * 8;
    }
    int ldsBase = wid * 512;

    for (int kt = 0; kt < FF / BK; ++kt) {
#pragma unroll
        for (int i = 0; i < 4; i++)
            gload16(aSrc[i] + kt * BK, &Als[i * 2048 + ldsBase]);
#pragma unroll
        for (int i = 0; i < 4; i++)
            gload16(bSrc[i] + kt * BK, &Bls[i * 2048 + ldsBase]);
        __syncthreads();
#pragma unroll
        for (int kk = 0; kk < 2; kk++) {
            bf16x8 af[4], bfr[4];
#pragma unroll
            for (int mi = 0; mi < 4; mi++) {
                int row = wr * 64 + mi * 16 + (lane & 15);
                int s = (kk * 4 + (lane >> 4)) ^ (row & 7);
                af[mi] = *reinterpret_cast<const bf16x8*>(&Als[row * BK + s * 8]);
            }
#pragma unroll
            for (int nj = 0; nj < 4; nj++) {
                int row = wc * 64 + nj * 16 + (lane & 15);
                int s = (kk * 4 + (lane >> 4)) ^ (row & 7);
                bfr[nj] = *reinterpret_cast<const bf16x8*>(&Bls[row * BK + s * 8]);
            }
#pragma unroll
            for (int mi = 0; mi < 4; mi++)
#pragma unroll
                for (int nj = 0; nj < 4; nj++)
                    acc[mi][nj] = __builtin_amdgcn_mfma_f32_16x16x32_bf16(af[mi], bfr[nj], acc[mi][nj], 0, 0, 0);
        }
        __syncthreads();
    }

#pragma unroll
    for (int mi = 0; mi < 4; mi++) {
#pragma unroll
        for (int r = 0; r < 4; r++) {
            int lrow = m0 + wr * 64 + mi * 16 + ((lane >> 4) << 2) + r;
            if (lrow >= cnt) continue;
            int rv = rows[off + lrow];
            float wgt = roww[off + lrow];
            float* op = out + (size_t)(rv >> 1) * DIM + n0 + wc * 64;
#pragma unroll
            for (int nj = 0; nj < 4; nj++)
                atomicAdd(&op[nj * 16 + (lane & 15)], wgt * acc[mi][nj][r]);
        }
    }
}

extern "C" void kernel_launch(void* const* d_in, const int* in_sizes, int n_in,
                              void* d_out, int out_size, void* d_ws, size_t ws_size,
                              hipStream_t stream) {
    const float* x  = (const float*)d_in[0];
    const float* Wr = (const float*)d_in[1];
    const float* W1 = (const float*)d_in[2];
    const float* W2 = (const float*)d_in[3];
    float* out = (float*)d_out;

    char* w = (char*)d_ws;
    size_t o = 0;
    auto carve = [&](size_t bytes) -> void* {
        void* p = w + o;
        o = (o + bytes + 255) & ~(size_t)255;
        return p;
    };
    int*   counts = (int*)carve(NE * 4);
    int*   offs   = (int*)carve(NE * 4);
    int*   cursor = (int*)carve(NE * 4);
    int*   topi   = (int*)carve((size_t)NT * 2 * 4);
    float* topw   = (float*)carve((size_t)NT * 2 * 4);
    int*   rows   = (int*)carve((size_t)NT * 2 * 4);
    float* roww   = (float*)carve((size_t)NT * 2 * 4);
    u16*   xbf    = (u16*)carve((size_t)NT * DIM * 2);
    u16*   w1t    = (u16*)carve((size_t)NE * DIM * FF * 2);
    u16*   w2t    = (u16*)carve((size_t)NE * DIM * FF * 2);
    u16*   Hbuf   = (u16*)carve((size_t)NT * 2 * FF * 2);
    (void)ws_size; (void)in_sizes; (void)n_in; (void)out_size;

    hipMemsetAsync(counts, 0, NE * 4, stream);
    hipMemsetAsync(d_out, 0, (size_t)NT * DIM * 4, stream);

    k_router<<<NT / 4, 256, 0, stream>>>(x, Wr, topi, topw, counts);
    k_prefix<<<1, 64, 0, stream>>>(counts, offs, cursor);
    k_build<<<NT / 256, 256, 0, stream>>>(topi, topw, cursor, rows, roww);
    k_cvt<<<(NT * DIM / 8) / 256, 256, 0, stream>>>(x, xbf, NT * DIM);
    {
        dim3 g(FF / 64, DIM / 64, NE);
        k_tcvt<<<g, 256, 0, stream>>>(W1, w1t, DIM, FF);
    }
    {
        dim3 g(DIM / 64, FF / 64, NE);
        k_tcvt<<<g, 256, 0, stream>>>(W2, w2t, FF, DIM);
    }
    {
        dim3 g(NT / BM, FF / BN, NE);
        k_gemm1<<<g, 256, 0, stream>>>(xbf, w1t, rows, offs, counts, Hbuf);
    }
    {
        dim3 g(NT / BM, DIM / BN, NE);
        k_gemm2<<<g, 256, 0, stream>>>(Hbuf, w2t, rows, roww, offs, counts, out);
    }
}

// Round 3
// 869.952 us; speedup vs baseline: 1.4805x; 1.4654x over previous
//
#include <hip/hip_runtime.h>
#include <hip/hip_bf16.h>

using u16 = unsigned short;
using u32 = unsigned int;

typedef __bf16 bf16x8 __attribute__((ext_vector_type(8)));
typedef float f32x4 __attribute__((ext_vector_type(4)));
typedef float f32x4v __attribute__((ext_vector_type(4)));
typedef unsigned short u16x8 __attribute__((ext_vector_type(8)));

constexpr int NT  = 8192;   // B*T tokens
constexpr int DIM = 1024;
constexpr int FF  = 4096;
constexpr int NE  = 8;      // experts

constexpr int BM = 128, BN = 128, BK = 64;
constexpr int MAXMB = 136;              // max m-blocks: NT*2/BM + NE
constexpr int G1X = MAXMB * (FF / BN);  // 136*32 = 4352  (%8==0)
constexpr int G2X = MAXMB * (DIM / BN); // 136*8  = 1088  (%8==0)

__device__ inline u16 f2bf(float f) {
    u32 u = __float_as_uint(f);
    u32 r = (u + 0x7fffu + ((u >> 16) & 1u)) >> 16;
    return (u16)r;
}

// direct global->LDS, 16B per lane, wave-uniform LDS base + lane*16
__device__ inline void gload16(const void* g, void* l) {
    __builtin_amdgcn_global_load_lds(
        (const __attribute__((address_space(1))) void*)g,
        (__attribute__((address_space(3))) void*)l, 16, 0, 0);
}

// ---------------- router: logits -> top2 -> softmax weights ----------------
__global__ __launch_bounds__(256) void k_router(const float* __restrict__ x,
                                                const float* __restrict__ Wr,
                                                int* __restrict__ topi,
                                                float* __restrict__ topw,
                                                int* __restrict__ counts) {
    int w = threadIdx.x >> 6, lane = threadIdx.x & 63;
    int t = blockIdx.x * 4 + w;
    const float* xt = x + (size_t)t * DIM;
    float acc[NE];
#pragma unroll
    for (int e = 0; e < NE; e++) acc[e] = 0.f;
    for (int i = 0; i < DIM / 64; i++) {
        int d = i * 64 + lane;
        float xv = xt[d];
#pragma unroll
        for (int e = 0; e < NE; e++) acc[e] += xv * Wr[e * DIM + d];
    }
#pragma unroll
    for (int e = 0; e < NE; e++) {
#pragma unroll
        for (int off = 32; off >= 1; off >>= 1) acc[e] += __shfl_xor(acc[e], off, 64);
    }
    if (lane == 0) {
        int b0 = 0; float v0 = acc[0];
        for (int e = 1; e < NE; e++) if (acc[e] > v0) { v0 = acc[e]; b0 = e; }
        int b1 = -1; float v1 = -INFINITY;
        for (int e = 0; e < NE; e++) if (e != b0 && acc[e] > v1) { v1 = acc[e]; b1 = e; }
        float e1 = __expf(v1 - v0);
        float w0 = 1.f / (1.f + e1);
        topi[t * 2] = b0; topi[t * 2 + 1] = b1;
        topw[t * 2] = w0; topw[t * 2 + 1] = 1.f - w0;
        atomicAdd(&counts[b0], 1);
        atomicAdd(&counts[b1], 1);
    }
}

// prefix + m-block table (expert id, local m0) for grid compaction
__global__ void k_prefix(const int* __restrict__ counts, int* __restrict__ offs,
                         int* __restrict__ cursor, int* __restrict__ tblE,
                         int* __restrict__ tblM, int* __restrict__ nmb) {
    if (threadIdx.x == 0) {
        int s = 0, idx = 0;
        for (int e = 0; e < NE; e++) {
            offs[e] = s; cursor[e] = s;
            int nb = (counts[e] + BM - 1) / BM;
            for (int b = 0; b < nb; b++) { tblE[idx] = e; tblM[idx] = b * BM; idx++; }
            s += counts[e];
        }
        *nmb = idx;
    }
}

__global__ __launch_bounds__(256) void k_build(const int* __restrict__ topi,
                                               const float* __restrict__ topw,
                                               int* __restrict__ cursor,
                                               int* __restrict__ rows,
                                               float* __restrict__ roww) {
    int t = blockIdx.x * 256 + threadIdx.x;
    if (t >= NT) return;
#pragma unroll
    for (int s = 0; s < 2; s++) {
        int e = topi[t * 2 + s];
        int p = atomicAdd(&cursor[e], 1);
        rows[p] = t * 2 + s;
        roww[p] = topw[t * 2 + s];
    }
}

// ---------------- fp32 -> bf16 convert (x) ----------------
__global__ __launch_bounds__(256) void k_cvt(const float* __restrict__ in,
                                             u16* __restrict__ out, int n) {
    int i = blockIdx.x * 256 + threadIdx.x;
    int base = i * 8;
    if (base >= n) return;
    const f32x4v* in4 = reinterpret_cast<const f32x4v*>(in + base);
    f32x4v a = in4[0], b = in4[1];
    u16x8 o;
#pragma unroll
    for (int j = 0; j < 4; j++) { o[j] = f2bf(a[j]); o[j + 4] = f2bf(b[j]); }
    *reinterpret_cast<u16x8*>(out + base) = o;
}

// ---------------- transpose + convert: in [R][C] fp32 -> out [C][R] bf16 ----------------
__global__ __launch_bounds__(256) void k_tcvt(const float* __restrict__ in,
                                              u16* __restrict__ out, int R, int C) {
    __shared__ float tile[64][65];
    int e = blockIdx.z;
    const float* pin = in + (size_t)e * R * C;
    u16* pout = out + (size_t)e * R * C;
    int c0 = blockIdx.x * 64, r0 = blockIdx.y * 64;
    int t = threadIdx.x;
    int lc = (t & 15) * 4, lr = t >> 4;
#pragma unroll
    for (int i = 0; i < 4; i++) {
        int r = lr + i * 16;
        f32x4v v = *reinterpret_cast<const f32x4v*>(&pin[(size_t)(r0 + r) * C + c0 + lc]);
        tile[r][lc] = v[0]; tile[r][lc + 1] = v[1];
        tile[r][lc + 2] = v[2]; tile[r][lc + 3] = v[3];
    }
    __syncthreads();
    int oc = (t & 7) * 8;
    int orow = t >> 3;
#pragma unroll
    for (int i = 0; i < 2; i++) {
        int cc = orow + i * 32;
        u16x8 o;
#pragma unroll
        for (int j = 0; j < 8; j++) o[j] = f2bf(tile[oc + j][cc]);
        *reinterpret_cast<u16x8*>(&pout[(size_t)(c0 + cc) * R + r0 + oc]) = o;
    }
}

// ---------------- GEMM1: H = gelu(x @ W1[e]); 2-phase dbuf pipeline ----------------
__global__ __launch_bounds__(256, 2) void k_gemm1(const u16* __restrict__ xbf,
                                                  const u16* __restrict__ w1t, // [E][FF][DIM]
                                                  const int* __restrict__ rows,
                                                  const int* __restrict__ offs,
                                                  const int* __restrict__ counts,
                                                  const int* __restrict__ tblE,
                                                  const int* __restrict__ tblM,
                                                  const int* __restrict__ nmb,
                                                  u16* __restrict__ H) {
    constexpr int NY = FF / BN;   // 32
    int nwg = G1X, cpx = nwg >> 3;
    int l = ((int)blockIdx.x & 7) * cpx + ((int)blockIdx.x >> 3);
    int xm = l >> 5, yn = l & 31;
    if (xm >= *nmb) return;
    int e = tblE[xm], m0 = tblM[xm];
    int cnt = counts[e], off = offs[e];
    int n0 = yn * BN;
    (void)NY;

    __shared__ __align__(16) u16 Als[2][BM * BK];
    __shared__ __align__(16) u16 Bls[2][BN * BK];

    int tid = threadIdx.x;
    int lane = tid & 63, wid = tid >> 6;
    int wr = wid >> 1, wc = wid & 1;

    f32x4 acc[4][4];
#pragma unroll
    for (int i = 0; i < 4; i++)
#pragma unroll
        for (int j = 0; j < 4; j++) acc[i][j] = (f32x4)(0.f);

    const u16* aSrc[4];
    const u16* bSrc[4];
#pragma unroll
    for (int i = 0; i < 4; i++) {
        int row = i * 32 + (tid >> 3);
        int g = (tid & 7) ^ (row & 7);
        int lrow = m0 + row;
        int tok = (lrow < cnt) ? (rows[off + lrow] >> 1) : 0;
        aSrc[i] = xbf + (size_t)tok * DIM + g * 8;
        bSrc[i] = w1t + (size_t)e * FF * DIM + (size_t)(n0 + row) * DIM + g * 8;
    }
    int ldsOff = wid * 512;   // elems; + i*2048 per chunk

#define STAGE1(buf, kt) do { \
    _Pragma("unroll") for (int i_ = 0; i_ < 4; i_++) \
        gload16(aSrc[i_] + (kt) * BK, &Als[buf][i_ * 2048 + ldsOff]); \
    _Pragma("unroll") for (int i_ = 0; i_ < 4; i_++) \
        gload16(bSrc[i_] + (kt) * BK, &Bls[buf][i_ * 2048 + ldsOff]); \
} while (0)

#define FRAGS1(cur) \
    bf16x8 af[2][4], bfr[2][4]; \
    { const u16* Ab = &Als[cur][0]; const u16* Bb = &Bls[cur][0]; \
    _Pragma("unroll") for (int kk = 0; kk < 2; kk++) { \
        _Pragma("unroll") for (int mi = 0; mi < 4; mi++) { \
            int row = wr * 64 + mi * 16 + (lane & 15); \
            int s = (kk * 4 + (lane >> 4)) ^ (row & 7); \
            af[kk][mi] = *reinterpret_cast<const bf16x8*>(&Ab[row * BK + s * 8]); } \
        _Pragma("unroll") for (int nj = 0; nj < 4; nj++) { \
            int row = wc * 64 + nj * 16 + (lane & 15); \
            int s = (kk * 4 + (lane >> 4)) ^ (row & 7); \
            bfr[kk][nj] = *reinterpret_cast<const bf16x8*>(&Bb[row * BK + s * 8]); } } }

#define MFMAS1() do { \
    __builtin_amdgcn_s_setprio(1); \
    _Pragma("unroll") for (int kk = 0; kk < 2; kk++) \
    _Pragma("unroll") for (int mi = 0; mi < 4; mi++) \
    _Pragma("unroll") for (int nj = 0; nj < 4; nj++) \
        acc[mi][nj] = __builtin_amdgcn_mfma_f32_16x16x32_bf16(af[kk][mi], bfr[kk][nj], acc[mi][nj], 0, 0, 0); \
    __builtin_amdgcn_s_setprio(0); \
} while (0)

    constexpr int NKT = DIM / BK;  // 16
    STAGE1(0, 0);
    STAGE1(1, 1);
    for (int kt = 0; kt < NKT - 1; ++kt) {
        int cur = kt & 1;
        asm volatile("s_waitcnt vmcnt(8)" ::: "memory");
        __builtin_amdgcn_s_barrier();
        __builtin_amdgcn_sched_barrier(0);
        FRAGS1(cur);
        asm volatile("s_waitcnt lgkmcnt(0)" ::: "memory");
        __builtin_amdgcn_sched_barrier(0);
        __builtin_amdgcn_s_barrier();
        __builtin_amdgcn_sched_barrier(0);
        if (kt + 2 < NKT) STAGE1(cur, kt + 2);
        MFMAS1();
    }
    {   // final K-step: everything outstanding must land
        asm volatile("s_waitcnt vmcnt(0)" ::: "memory");
        __builtin_amdgcn_s_barrier();
        __builtin_amdgcn_sched_barrier(0);
        FRAGS1((NKT - 1) & 1);
        MFMAS1();
    }
#undef STAGE1
#undef FRAGS1
#undef MFMAS1

    // epilogue: exact GELU -> bf16 H
#pragma unroll
    for (int mi = 0; mi < 4; mi++) {
#pragma unroll
        for (int r = 0; r < 4; r++) {
            int lrow = m0 + wr * 64 + mi * 16 + ((lane >> 4) << 2) + r;
            if (lrow >= cnt) continue;
            u16* hp = H + (size_t)(off + lrow) * FF + n0 + wc * 64;
#pragma unroll
            for (int nj = 0; nj < 4; nj++) {
                float v = acc[mi][nj][r];
                v = 0.5f * v * (1.f + erff(v * 0.70710678118f));
                hp[nj * 16 + (lane & 15)] = f2bf(v);
            }
        }
    }
}

// ---------------- GEMM2: out[token] += w * (H[row] @ W2[e]) ----------------
__global__ __launch_bounds__(256, 2) void k_gemm2(const u16* __restrict__ H,
                                                  const u16* __restrict__ w2t, // [E][DIM][FF]
                                                  const int* __restrict__ rows,
                                                  const float* __restrict__ roww,
                                                  const int* __restrict__ offs,
                                                  const int* __restrict__ counts,
                                                  const int* __restrict__ tblE,
                                                  const int* __restrict__ tblM,
                                                  const int* __restrict__ nmb,
                                                  float* __restrict__ out) {
    int nwg = G2X, cpx = nwg >> 3;
    int l = ((int)blockIdx.x & 7) * cpx + ((int)blockIdx.x >> 3);
    int xm = l >> 3, yn = l & 7;
    if (xm >= *nmb) return;
    int e = tblE[xm], m0 = tblM[xm];
    int cnt = counts[e], off = offs[e];
    int n0 = yn * BN;

    __shared__ __align__(16) u16 Als[2][BM * BK];
    __shared__ __align__(16) u16 Bls[2][BN * BK];

    int tid = threadIdx.x;
    int lane = tid & 63, wid = tid >> 6;
    int wr = wid >> 1, wc = wid & 1;

    f32x4 acc[4][4];
#pragma unroll
    for (int i = 0; i < 4; i++)
#pragma unroll
        for (int j = 0; j < 4; j++) acc[i][j] = (f32x4)(0.f);

    const u16* aSrc[4];
    const u16* bSrc[4];
#pragma unroll
    for (int i = 0; i < 4; i++) {
        int row = i * 32 + (tid >> 3);
        int g = (tid & 7) ^ (row & 7);
        int lrow = m0 + row;
        int grow = off + ((lrow < cnt) ? lrow : (cnt - 1));
        aSrc[i] = H + (size_t)grow * FF + g * 8;
        bSrc[i] = w2t + (size_t)e * DIM * FF + (size_t)(n0 + row) * FF + g * 8;
    }
    int ldsOff = wid * 512;

#define STAGE2(buf, kt) do { \
    _Pragma("unroll") for (int i_ = 0; i_ < 4; i_++) \
        gload16(aSrc[i_] + (kt) * BK, &Als[buf][i_ * 2048 + ldsOff]); \
    _Pragma("unroll") for (int i_ = 0; i_ < 4; i_++) \
        gload16(bSrc[i_] + (kt) * BK, &Bls[buf][i_ * 2048 + ldsOff]); \
} while (0)

#define FRAGS2(cur) \
    bf16x8 af[2][4], bfr[2][4]; \
    { const u16* Ab = &Als[cur][0]; const u16* Bb = &Bls[cur][0]; \
    _Pragma("unroll") for (int kk = 0; kk < 2; kk++) { \
        _Pragma("unroll") for (int mi = 0; mi < 4; mi++) { \
            int row = wr * 64 + mi * 16 + (lane & 15); \
            int s = (kk * 4 + (lane >> 4)) ^ (row & 7); \
            af[kk][mi] = *reinterpret_cast<const bf16x8*>(&Ab[row * BK + s * 8]); } \
        _Pragma("unroll") for (int nj = 0; nj < 4; nj++) { \
            int row = wc * 64 + nj * 16 + (lane & 15); \
            int s = (kk * 4 + (lane >> 4)) ^ (row & 7); \
            bfr[kk][nj] = *reinterpret_cast<const bf16x8*>(&Bb[row * BK + s * 8]); } } }

#define MFMAS2() do { \
    __builtin_amdgcn_s_setprio(1); \
    _Pragma("unroll") for (int kk = 0; kk < 2; kk++) \
    _Pragma("unroll") for (int mi = 0; mi < 4; mi++) \
    _Pragma("unroll") for (int nj = 0; nj < 4; nj++) \
        acc[mi][nj] = __builtin_amdgcn_mfma_f32_16x16x32_bf16(af[kk][mi], bfr[kk][nj], acc[mi][nj], 0, 0, 0); \
    __builtin_amdgcn_s_setprio(0); \
} while (0)

    constexpr int NKT = FF / BK;  // 64
    STAGE2(0, 0);
    STAGE2(1, 1);
    for (int kt = 0; kt < NKT - 1; ++kt) {
        int cur = kt & 1;
        asm volatile("s_waitcnt vmcnt(8)" ::: "memory");
        __builtin_amdgcn_s_barrier();
        __builtin_amdgcn_sched_barrier(0);
        FRAGS2(cur);
        asm volatile("s_waitcnt lgkmcnt(0)" ::: "memory");
        __builtin_amdgcn_sched_barrier(0);
        __builtin_amdgcn_s_barrier();
        __builtin_amdgcn_sched_barrier(0);
        if (kt + 2 < NKT) STAGE2(cur, kt + 2);
        MFMAS2();
    }
    {
        asm volatile("s_waitcnt vmcnt(0)" ::: "memory");
        __builtin_amdgcn_s_barrier();
        __builtin_amdgcn_sched_barrier(0);
        FRAGS2((NKT - 1) & 1);
        MFMAS2();
    }
#undef STAGE2
#undef FRAGS2
#undef MFMAS2

#pragma unroll
    for (int mi = 0; mi < 4; mi++) {
#pragma unroll
        for (int r = 0; r < 4; r++) {
            int lrow = m0 + wr * 64 + mi * 16 + ((lane >> 4) << 2) + r;
            if (lrow >= cnt) continue;
            int rv = rows[off + lrow];
            float wgt = roww[off + lrow];
            float* op = out + (size_t)(rv >> 1) * DIM + n0 + wc * 64;
#pragma unroll
            for (int nj = 0; nj < 4; nj++)
                atomicAdd(&op[nj * 16 + (lane & 15)], wgt * acc[mi][nj][r]);
        }
    }
}

extern "C" void kernel_launch(void* const* d_in, const int* in_sizes, int n_in,
                              void* d_out, int out_size, void* d_ws, size_t ws_size,
                              hipStream_t stream) {
    const float* x  = (const float*)d_in[0];
    const float* Wr = (const float*)d_in[1];
    const float* W1 = (const float*)d_in[2];
    const float* W2 = (const float*)d_in[3];
    float* out = (float*)d_out;

    char* w = (char*)d_ws;
    size_t o = 0;
    auto carve = [&](size_t bytes) -> void* {
        void* p = w + o;
        o = (o + bytes + 255) & ~(size_t)255;
        return p;
    };
    int*   counts = (int*)carve(NE * 4);
    int*   offs   = (int*)carve(NE * 4);
    int*   cursor = (int*)carve(NE * 4);
    int*   tblE   = (int*)carve(MAXMB * 4);
    int*   tblM   = (int*)carve(MAXMB * 4);
    int*   nmb    = (int*)carve(4);
    int*   topi   = (int*)carve((size_t)NT * 2 * 4);
    float* topw   = (float*)carve((size_t)NT * 2 * 4);
    int*   rows   = (int*)carve((size_t)NT * 2 * 4);
    float* roww   = (float*)carve((size_t)NT * 2 * 4);
    u16*   xbf    = (u16*)carve((size_t)NT * DIM * 2);
    u16*   w1t    = (u16*)carve((size_t)NE * DIM * FF * 2);
    u16*   w2t    = (u16*)carve((size_t)NE * DIM * FF * 2);
    u16*   Hbuf   = (u16*)carve((size_t)NT * 2 * FF * 2);
    (void)ws_size; (void)in_sizes; (void)n_in; (void)out_size;

    hipMemsetAsync(counts, 0, NE * 4, stream);
    hipMemsetAsync(d_out, 0, (size_t)NT * DIM * 4, stream);

    k_router<<<NT / 4, 256, 0, stream>>>(x, Wr, topi, topw, counts);
    k_prefix<<<1, 64, 0, stream>>>(counts, offs, cursor, tblE, tblM, nmb);
    k_build<<<NT / 256, 256, 0, stream>>>(topi, topw, cursor, rows, roww);
    k_cvt<<<(NT * DIM / 8) / 256, 256, 0, stream>>>(x, xbf, NT * DIM);
    {
        dim3 g(FF / 64, DIM / 64, NE);
        k_tcvt<<<g, 256, 0, stream>>>(W1, w1t, DIM, FF);
    }
    {
        dim3 g(DIM / 64, FF / 64, NE);
        k_tcvt<<<g, 256, 0, stream>>>(W2, w2t, FF, DIM);
    }
    k_gemm1<<<G1X, 256, 0, stream>>>(xbf, w1t, rows, offs, counts, tblE, tblM, nmb, Hbuf);
    k_gemm2<<<G2X, 256, 0, stream>>>(Hbuf, w2t, rows, roww, offs, counts, tblE, tblM, nmb, out);
}